// Round 3
// baseline (1482.503 us; speedup 1.0000x reference)
//
#include <hip/hip_runtime.h>
#include <hip/hip_bf16.h>

#define F_DIM 128
#define N_RBF 20
#define CUTOFF 5.0f
#define PI_F 3.14159265358979323846f
#define NPB 4   // nodes per k_edge block

// ---------------------------------------------------------------------------
__global__ __launch_bounds__(256) void k_rowptr(const int* __restrict__ idx_i,
                                                int* __restrict__ row_ptr, int N, int E) {
    int i = blockIdx.x * blockDim.x + threadIdx.x;
    if (i > N) return;
    if (i == N) { row_ptr[N] = E; return; }
    int lo = 0, hi = E;
    while (lo < hi) {
        int mid = (lo + hi) >> 1;
        if (idx_i[mid] < i) lo = mid + 1; else hi = mid;
    }
    row_ptr[i] = lo;
}

// ---------------------------------------------------------------------------
__global__ __launch_bounds__(256) void k_init(const int* __restrict__ Z,
                                              const float* __restrict__ emb,
                                              float* __restrict__ q,
                                              float* __restrict__ muA, int N) {
    int idx = blockIdx.x * blockDim.x + threadIdx.x;
    if (idx < N * F_DIM) {
        int n = idx >> 7, f = idx & 127;
        q[idx] = emb[Z[n] * F_DIM + f];
    }
    if (idx < N * 3 * F_DIM) muA[idx] = 0.f;
}

// ---------------------------------------------------------------------------
__global__ __launch_bounds__(256) void k_geom(const float* __restrict__ r,
                                              float* __restrict__ geom, int E) {
    int e = blockIdx.x * blockDim.x + threadIdx.x;
    if (e >= E) return;
    float x = r[e * 3], y = r[e * 3 + 1], z = r[e * 3 + 2];
    float d = sqrtf(x * x + y * y + z * z);
    float inv = 1.f / d;
    float fc = (d < CUTOFF) ? 0.5f * (__cosf(d * (PI_F / CUTOFF)) + 1.f) : 0.f;
    float* g = geom + (size_t)e * 24;
    g[0] = x * inv; g[1] = y * inv; g[2] = z * inv; g[3] = fc;
    const float delta = CUTOFF / (N_RBF - 1);
    const float coeff = -0.5f / (delta * delta);
#pragma unroll
    for (int k = 0; k < N_RBF; k++) {
        float t = d - k * delta;
        g[4 + k] = __expf(coeff * t * t) * fc;
    }
}

// ---------------------------------------------------------------------------
// x = silu(q@W1 + b1)@W2 + b2     16 nodes / block; LDS reads via float4
__global__ __launch_bounds__(256) void k_node_msg(const float* __restrict__ q,
                                                  const float* __restrict__ W1,
                                                  const float* __restrict__ b1,
                                                  const float* __restrict__ W2,
                                                  const float* __restrict__ b2,
                                                  float* __restrict__ x, int N) {
    __shared__ float qs[16][128];
    __shared__ float hs[16][128];
    int n0 = blockIdx.x * 16;
    int t = threadIdx.x;
    int f = t & 127, nb = t >> 7;

    for (int r = 0; r < 8; r++) {
        int idx = r * 256 + t;
        int n = idx >> 7, ff = idx & 127;
        int gn = n0 + n;
        qs[n][ff] = (gn < N) ? q[(size_t)gn * 128 + ff] : 0.f;
    }
    __syncthreads();

    {   // h = silu(q@W1 + b1)
        float acc[8];
#pragma unroll
        for (int r = 0; r < 8; r++) acc[r] = b1[f];
        for (int k4 = 0; k4 < 128; k4 += 4) {
            float w0 = W1[(k4 + 0) * 128 + f];
            float w1 = W1[(k4 + 1) * 128 + f];
            float w2 = W1[(k4 + 2) * 128 + f];
            float w3 = W1[(k4 + 3) * 128 + f];
#pragma unroll
            for (int r = 0; r < 8; r++) {
                float4 qv = *(const float4*)&qs[2 * r + nb][k4];
                acc[r] += qv.x * w0 + qv.y * w1 + qv.z * w2 + qv.w * w3;
            }
        }
#pragma unroll
        for (int r = 0; r < 8; r++) {
            float a = acc[r];
            hs[2 * r + nb][f] = a / (1.f + __expf(-a));
        }
    }
    __syncthreads();

    {   // x = h@W2 + b2
        float x0[8], x1[8], x2[8];
#pragma unroll
        for (int r = 0; r < 8; r++) { x0[r] = b2[f]; x1[r] = b2[128 + f]; x2[r] = b2[256 + f]; }
        for (int k4 = 0; k4 < 128; k4 += 4) {
            float wa[4], wb[4], wc[4];
#pragma unroll
            for (int u = 0; u < 4; u++) {
                wa[u] = W2[(k4 + u) * 384 + f];
                wb[u] = W2[(k4 + u) * 384 + 128 + f];
                wc[u] = W2[(k4 + u) * 384 + 256 + f];
            }
#pragma unroll
            for (int r = 0; r < 8; r++) {
                float4 hv = *(const float4*)&hs[2 * r + nb][k4];
                x0[r] += hv.x * wa[0] + hv.y * wa[1] + hv.z * wa[2] + hv.w * wa[3];
                x1[r] += hv.x * wb[0] + hv.y * wb[1] + hv.z * wb[2] + hv.w * wb[3];
                x2[r] += hv.x * wc[0] + hv.y * wc[1] + hv.z * wc[2] + hv.w * wc[3];
            }
        }
#pragma unroll
        for (int r = 0; r < 8; r++) {
            int gn = n0 + 2 * r + nb;
            if (gn < N) {
                size_t base = (size_t)gn * 384;
                x[base + f] = x0[r];
                x[base + 128 + f] = x1[r];
                x[base + 256 + f] = x2[r];
            }
        }
    }
}

// ---------------------------------------------------------------------------
// Edge aggregation: NPB nodes / block, CSR, no atomics. Software-pipelined:
// next edge's idx_j, geom, and gathered x/mu are prefetched during the
// current edge's 63-FMA filter block, so no dependent-load stall in
// steady state. Filter weights in registers, amortized over NPB nodes.
__global__ __launch_bounds__(256) void k_edge(const float* __restrict__ x,
                                              const float* __restrict__ mu_in,
                                              const float* __restrict__ geom,
                                              const int* __restrict__ idx_j,
                                              const int* __restrict__ row_ptr,
                                              const float* __restrict__ filt_W,
                                              const float* __restrict__ filt_b,
                                              int layer,
                                              float* __restrict__ q,
                                              float* __restrict__ mu_out, int N) {
    __shared__ float red[4][128];
    int t = threadIdx.x;
    int f = t & 127, sub = t >> 7;

    float Wfr0[N_RBF], Wfr1[N_RBF], Wfr2[N_RBF];
    const float* Wbase = filt_W + layer * 384;
#pragma unroll
    for (int k = 0; k < N_RBF; k++) {
        Wfr0[k] = Wbase[k * 1152 + f];
        Wfr1[k] = Wbase[k * 1152 + 128 + f];
        Wfr2[k] = Wbase[k * 1152 + 256 + f];
    }
    float bf0 = filt_b[layer * 384 + f];
    float bf1 = filt_b[layer * 384 + 128 + f];
    float bf2 = filt_b[layer * 384 + 256 + f];

    int i0 = blockIdx.x * NPB;
    for (int nn = 0; nn < NPB; nn++) {
        int i = i0 + nn;
        if (i >= N) break;
        int rs = row_ptr[i], re = row_ptr[i + 1];
        float dq = 0.f, dm0 = 0.f, dm1 = 0.f, dm2 = 0.f;

        int e = rs + sub;
        if (e < re) {
            // prologue: full load of first edge
            int j = idx_j[e];
            const float4* g4 = (const float4*)(geom + (size_t)e * 24);
            float4 a = g4[0], p0 = g4[1], p1 = g4[2], p2 = g4[3], p3 = g4[4], p4 = g4[5];
            const float* xj = x + (size_t)j * 384;
            const float* mj = mu_in + (size_t)j * 384;
            float xq = xj[f], xr = xj[128 + f], xm = xj[256 + f];
            float m0 = mj[f], m1 = mj[128 + f], m2 = mj[256 + f];
            int en = e + 2;
            while (true) {
                bool vn = en < re;
                int jn = 0;
                float4 an, pn0, pn1, pn2, pn3, pn4;
                float xqn, xrn, xmn, m0n, m1n, m2n;
                if (vn) {  // prefetch next edge completely (issued before compute)
                    jn = idx_j[en];
                    const float4* g4n = (const float4*)(geom + (size_t)en * 24);
                    an = g4n[0]; pn0 = g4n[1]; pn1 = g4n[2]; pn2 = g4n[3]; pn3 = g4n[4]; pn4 = g4n[5];
                    const float* xjn = x + (size_t)jn * 384;
                    const float* mjn = mu_in + (size_t)jn * 384;
                    xqn = xjn[f]; xrn = xjn[128 + f]; xmn = xjn[256 + f];
                    m0n = mjn[f]; m1n = mjn[128 + f]; m2n = mjn[256 + f];
                }
                // compute current edge (all operands in registers)
                float wq = a.w * bf0, wr = a.w * bf1, wm = a.w * bf2;
                float ph[N_RBF] = {p0.x, p0.y, p0.z, p0.w, p1.x, p1.y, p1.z, p1.w,
                                   p2.x, p2.y, p2.z, p2.w, p3.x, p3.y, p3.z, p3.w,
                                   p4.x, p4.y, p4.z, p4.w};
#pragma unroll
                for (int k = 0; k < N_RBF; k++) {
                    wq += ph[k] * Wfr0[k];
                    wr += ph[k] * Wfr1[k];
                    wm += ph[k] * Wfr2[k];
                }
                dq += wq * xq;
                float s_r = wr * xr, s_m = wm * xm;
                dm0 += s_r * a.x + s_m * m0;
                dm1 += s_r * a.y + s_m * m1;
                dm2 += s_r * a.z + s_m * m2;
                if (!vn) break;
                a = an; p0 = pn0; p1 = pn1; p2 = pn2; p3 = pn3; p4 = pn4;
                xq = xqn; xr = xrn; xm = xmn; m0 = m0n; m1 = m1n; m2 = m2n;
                en += 2;
            }
        }

        if (sub == 1) { red[0][f] = dq; red[1][f] = dm0; red[2][f] = dm1; red[3][f] = dm2; }
        __syncthreads();
        if (sub == 0) {
            dq += red[0][f]; dm0 += red[1][f]; dm1 += red[2][f]; dm2 += red[3][f];
            q[(size_t)i * 128 + f] += dq;
            size_t base = (size_t)i * 384;
            mu_out[base + f]       = mu_in[base + f] + dm0;
            mu_out[base + 128 + f] = mu_in[base + 128 + f] + dm1;
            mu_out[base + 256 + f] = mu_in[base + 256 + f] + dm2;
        }
        __syncthreads();
    }
}

// ---------------------------------------------------------------------------
// Mixing block: 8 nodes / block; LDS reads via float4
__global__ __launch_bounds__(256) void k_mix(float* __restrict__ q,
                                             float* __restrict__ mu,
                                             const float* __restrict__ muxW,
                                             const float* __restrict__ W1,
                                             const float* __restrict__ b1,
                                             const float* __restrict__ W2,
                                             const float* __restrict__ b2, int N) {
    __shared__ float mus[8][3][128];
    __shared__ float qs[8][128];
    __shared__ float Vs[8][3][128];
    __shared__ float Ws_[8][3][128];
    __shared__ float vns[8][128];
    __shared__ float hs[8][128];
    int n0 = blockIdx.x * 8;
    int t = threadIdx.x;
    int f = t & 127, nb = t >> 7;

    for (int idx = t; idx < 3072; idx += 256) {
        int n = idx / 384, rem = idx % 384;
        int gn = n0 + n;
        ((float*)mus)[idx] = (gn < N) ? mu[(size_t)gn * 384 + rem] : 0.f;
    }
    for (int idx = t; idx < 1024; idx += 256) {
        int n = idx >> 7, ff = idx & 127;
        int gn = n0 + n;
        qs[n][ff] = (gn < N) ? q[(size_t)gn * 128 + ff] : 0.f;
    }
    __syncthreads();

    {   // mu_mix = mu @ muxW : nb==0 computes V cols, nb==1 the W cols
        float acc[8][3];
#pragma unroll
        for (int n = 0; n < 8; n++)
#pragma unroll
            for (int c = 0; c < 3; c++) acc[n][c] = 0.f;
        for (int k4 = 0; k4 < 128; k4 += 4) {
            float w0 = muxW[(k4 + 0) * 256 + nb * 128 + f];
            float w1 = muxW[(k4 + 1) * 256 + nb * 128 + f];
            float w2 = muxW[(k4 + 2) * 256 + nb * 128 + f];
            float w3 = muxW[(k4 + 3) * 256 + nb * 128 + f];
#pragma unroll
            for (int n = 0; n < 8; n++) {
#pragma unroll
                for (int c = 0; c < 3; c++) {
                    float4 mv = *(const float4*)&mus[n][c][k4];
                    acc[n][c] += mv.x * w0 + mv.y * w1 + mv.z * w2 + mv.w * w3;
                }
            }
        }
        if (nb == 0) {
#pragma unroll
            for (int n = 0; n < 8; n++)
#pragma unroll
                for (int c = 0; c < 3; c++) Vs[n][c][f] = acc[n][c];
        } else {
#pragma unroll
            for (int n = 0; n < 8; n++)
#pragma unroll
                for (int c = 0; c < 3; c++) Ws_[n][c][f] = acc[n][c];
        }
    }
    __syncthreads();

    for (int idx = t; idx < 1024; idx += 256) {
        int n = idx >> 7, ff = idx & 127;
        float v0 = Vs[n][0][ff], v1 = Vs[n][1][ff], v2 = Vs[n][2][ff];
        vns[n][ff] = sqrtf(v0 * v0 + v1 * v1 + v2 * v2 + 1e-8f);
    }
    __syncthreads();

    {   // h = silu([q, vn] @ W1 + b1)
        float acc[4];
#pragma unroll
        for (int r = 0; r < 4; r++) acc[r] = b1[f];
        for (int k4 = 0; k4 < 128; k4 += 4) {
            float w0 = W1[(k4 + 0) * 128 + f];
            float w1 = W1[(k4 + 1) * 128 + f];
            float w2 = W1[(k4 + 2) * 128 + f];
            float w3 = W1[(k4 + 3) * 128 + f];
#pragma unroll
            for (int r = 0; r < 4; r++) {
                float4 qv = *(const float4*)&qs[2 * r + nb][k4];
                acc[r] += qv.x * w0 + qv.y * w1 + qv.z * w2 + qv.w * w3;
            }
        }
        for (int k4 = 0; k4 < 128; k4 += 4) {
            float w0 = W1[(128 + k4 + 0) * 128 + f];
            float w1 = W1[(128 + k4 + 1) * 128 + f];
            float w2 = W1[(128 + k4 + 2) * 128 + f];
            float w3 = W1[(128 + k4 + 3) * 128 + f];
#pragma unroll
            for (int r = 0; r < 4; r++) {
                float4 vv = *(const float4*)&vns[2 * r + nb][k4];
                acc[r] += vv.x * w0 + vv.y * w1 + vv.z * w2 + vv.w * w3;
            }
        }
#pragma unroll
        for (int r = 0; r < 4; r++) {
            float a = acc[r];
            hs[2 * r + nb][f] = a / (1.f + __expf(-a));
        }
    }
    __syncthreads();

    {   // x = h @ W2 + b2 ; then update q, mu
        float x0[4], x1[4], x2[4];
#pragma unroll
        for (int r = 0; r < 4; r++) { x0[r] = b2[f]; x1[r] = b2[128 + f]; x2[r] = b2[256 + f]; }
        for (int k4 = 0; k4 < 128; k4 += 4) {
            float wa[4], wb[4], wc[4];
#pragma unroll
            for (int u = 0; u < 4; u++) {
                wa[u] = W2[(k4 + u) * 384 + f];
                wb[u] = W2[(k4 + u) * 384 + 128 + f];
                wc[u] = W2[(k4 + u) * 384 + 256 + f];
            }
#pragma unroll
            for (int r = 0; r < 4; r++) {
                float4 hv = *(const float4*)&hs[2 * r + nb][k4];
                x0[r] += hv.x * wa[0] + hv.y * wa[1] + hv.z * wa[2] + hv.w * wa[3];
                x1[r] += hv.x * wb[0] + hv.y * wb[1] + hv.z * wb[2] + hv.w * wb[3];
                x2[r] += hv.x * wc[0] + hv.y * wc[1] + hv.z * wc[2] + hv.w * wc[3];
            }
        }
#pragma unroll
        for (int r = 0; r < 4; r++) {
            int n = 2 * r + nb;
            int gn = n0 + n;
            if (gn >= N) continue;
            float S = Vs[n][0][f] * Ws_[n][0][f] + Vs[n][1][f] * Ws_[n][1][f] +
                      Vs[n][2][f] * Ws_[n][2][f];
            q[(size_t)gn * 128 + f] = qs[n][f] + x0[r] + x2[r] * S;
            size_t base = (size_t)gn * 384;
#pragma unroll
            for (int c = 0; c < 3; c++)
                mu[base + c * 128 + f] = mus[n][c][f] + x1[r] * Ws_[n][c][f];
        }
    }
}

// ---------------------------------------------------------------------------
extern "C" void kernel_launch(void* const* d_in, const int* in_sizes, int n_in,
                              void* d_out, int out_size, void* d_ws, size_t ws_size,
                              hipStream_t stream) {
    const int*   Z      = (const int*)d_in[0];
    const float* r_ij   = (const float*)d_in[1];
    const int*   idx_i  = (const int*)d_in[2];
    const int*   idx_j  = (const int*)d_in[3];
    const float* emb    = (const float*)d_in[4];
    const float* filt_W = (const float*)d_in[5];
    const float* filt_b = (const float*)d_in[6];
    const float* int_W1 = (const float*)d_in[7];
    const float* int_b1 = (const float*)d_in[8];
    const float* int_W2 = (const float*)d_in[9];
    const float* int_b2 = (const float*)d_in[10];
    const float* mix_W1 = (const float*)d_in[11];
    const float* mix_b1 = (const float*)d_in[12];
    const float* mix_W2 = (const float*)d_in[13];
    const float* mix_b2 = (const float*)d_in[14];
    const float* mux_W  = (const float*)d_in[15];

    int N = in_sizes[0];
    int E = in_sizes[2];

    float* q   = (float*)d_out;              // [N,128]
    float* muD = q + (size_t)N * 128;        // [N,3,128]

    float* ws   = (float*)d_ws;
    float* geom = ws;                          // E*24
    float* xbuf = geom + (size_t)E * 24;       // N*384
    float* muA  = xbuf + (size_t)N * 384;      // N*384
    int* row_ptr = (int*)(muA + (size_t)N * 384);  // N+1

    k_rowptr<<<(N + 1 + 255) / 256, 256, 0, stream>>>(idx_i, row_ptr, N, E);
    k_init<<<((size_t)N * 384 + 255) / 256, 256, 0, stream>>>(Z, emb, q, muA, N);
    k_geom<<<(E + 255) / 256, 256, 0, stream>>>(r_ij, geom, E);

    float* mu_in = muA;
    float* mu_out = muD;
    for (int l = 0; l < 3; l++) {
        k_node_msg<<<(N + 15) / 16, 256, 0, stream>>>(
            q, int_W1 + (size_t)l * 128 * 128, int_b1 + l * 128,
            int_W2 + (size_t)l * 128 * 384, int_b2 + l * 384, xbuf, N);
        k_edge<<<(N + NPB - 1) / NPB, 256, 0, stream>>>(
            xbuf, mu_in, geom, idx_j, row_ptr, filt_W, filt_b, l, q, mu_out, N);
        k_mix<<<(N + 7) / 8, 256, 0, stream>>>(
            q, mu_out, mux_W + (size_t)l * 128 * 256,
            mix_W1 + (size_t)l * 256 * 128, mix_b1 + l * 128,
            mix_W2 + (size_t)l * 128 * 384, mix_b2 + l * 384, N);
        float* tmp = mu_in; mu_in = mu_out; mu_out = tmp;
    }
}

// Round 4
// 1056.200 us; speedup vs baseline: 1.4036x; 1.4036x over previous
//
#include <hip/hip_runtime.h>
#include <hip/hip_bf16.h>

#define F_DIM 128
#define N_RBF 20
#define CUTOFF 5.0f
#define PI_F 3.14159265358979323846f
#define NPB 4   // nodes per k_edge block

typedef float v2f __attribute__((ext_vector_type(2)));

// ---------------------------------------------------------------------------
__global__ __launch_bounds__(256) void k_rowptr(const int* __restrict__ idx_i,
                                                int* __restrict__ row_ptr, int N, int E) {
    int i = blockIdx.x * blockDim.x + threadIdx.x;
    if (i > N) return;
    if (i == N) { row_ptr[N] = E; return; }
    int lo = 0, hi = E;
    while (lo < hi) {
        int mid = (lo + hi) >> 1;
        if (idx_i[mid] < i) lo = mid + 1; else hi = mid;
    }
    row_ptr[i] = lo;
}

// ---------------------------------------------------------------------------
__global__ __launch_bounds__(256) void k_init(const int* __restrict__ Z,
                                              const float* __restrict__ emb,
                                              float* __restrict__ q,
                                              float* __restrict__ muA, int N) {
    int idx = blockIdx.x * blockDim.x + threadIdx.x;
    if (idx < N * F_DIM) {
        int n = idx >> 7, f = idx & 127;
        q[idx] = emb[Z[n] * F_DIM + f];
    }
    if (idx < N * 3 * F_DIM) muA[idx] = 0.f;
}

// ---------------------------------------------------------------------------
__global__ __launch_bounds__(256) void k_geom(const float* __restrict__ r,
                                              float* __restrict__ geom, int E) {
    int e = blockIdx.x * blockDim.x + threadIdx.x;
    if (e >= E) return;
    float x = r[e * 3], y = r[e * 3 + 1], z = r[e * 3 + 2];
    float d = sqrtf(x * x + y * y + z * z);
    float inv = 1.f / d;
    float fc = (d < CUTOFF) ? 0.5f * (__cosf(d * (PI_F / CUTOFF)) + 1.f) : 0.f;
    float* g = geom + (size_t)e * 24;
    g[0] = x * inv; g[1] = y * inv; g[2] = z * inv; g[3] = fc;
    const float delta = CUTOFF / (N_RBF - 1);
    const float coeff = -0.5f / (delta * delta);
#pragma unroll
    for (int k = 0; k < N_RBF; k++) {
        float t = d - k * delta;
        g[4 + k] = __expf(coeff * t * t) * fc;
    }
}

// ---------------------------------------------------------------------------
// x = silu(q@W1 + b1)@W2 + b2     16 nodes / block, 256 threads  (R2 version)
__global__ __launch_bounds__(256) void k_node_msg(const float* __restrict__ q,
                                                  const float* __restrict__ W1,
                                                  const float* __restrict__ b1,
                                                  const float* __restrict__ W2,
                                                  const float* __restrict__ b2,
                                                  float* __restrict__ x, int N) {
    __shared__ float qs[16][128];
    __shared__ float hs[16][128];
    int n0 = blockIdx.x * 16;
    int t = threadIdx.x;
    int f = t & 127, nb = t >> 7;

    for (int r = 0; r < 8; r++) {
        int idx = r * 256 + t;
        int n = idx >> 7, ff = idx & 127;
        int gn = n0 + n;
        qs[n][ff] = (gn < N) ? q[(size_t)gn * 128 + ff] : 0.f;
    }
    __syncthreads();

    {   // h = silu(q@W1 + b1)
        float acc[8];
#pragma unroll
        for (int r = 0; r < 8; r++) acc[r] = b1[f];
        for (int k = 0; k < 128; k++) {
            float w = W1[k * 128 + f];
#pragma unroll
            for (int r = 0; r < 8; r++) acc[r] += qs[2 * r + nb][k] * w;
        }
#pragma unroll
        for (int r = 0; r < 8; r++) {
            float a = acc[r];
            hs[2 * r + nb][f] = a / (1.f + __expf(-a));
        }
    }
    __syncthreads();

    {   // x = h@W2 + b2
        float x0[8], x1[8], x2[8];
#pragma unroll
        for (int r = 0; r < 8; r++) { x0[r] = b2[f]; x1[r] = b2[128 + f]; x2[r] = b2[256 + f]; }
        for (int k = 0; k < 128; k++) {
            float w0 = W2[k * 384 + f];
            float w1 = W2[k * 384 + 128 + f];
            float w2 = W2[k * 384 + 256 + f];
#pragma unroll
            for (int r = 0; r < 8; r++) {
                float h = hs[2 * r + nb][k];
                x0[r] += h * w0; x1[r] += h * w1; x2[r] += h * w2;
            }
        }
#pragma unroll
        for (int r = 0; r < 8; r++) {
            int gn = n0 + 2 * r + nb;
            if (gn < N) {
                size_t base = (size_t)gn * 384;
                x[base + f] = x0[r];
                x[base + 128 + f] = x1[r];
                x[base + 256 + f] = x2[r];
            }
        }
    }
}

// ---------------------------------------------------------------------------
// Edge aggregation: NPB nodes / block (amortizes filter preload), CSR, no
// atomics, simple inner loop (no manual pipelining — R3 showed the VGPR
// cost kills occupancy). Filter GEMV uses packed fp32 (v_pk_fma_f32):
// 10 v2f pairs per chunk instead of 20 scalar FMAs.
__global__ __launch_bounds__(256) void k_edge(const float* __restrict__ x,
                                              const float* __restrict__ mu_in,
                                              const float* __restrict__ geom,
                                              const int* __restrict__ idx_j,
                                              const int* __restrict__ row_ptr,
                                              const float* __restrict__ filt_W,
                                              const float* __restrict__ filt_b,
                                              int layer,
                                              float* __restrict__ q,
                                              float* __restrict__ mu_out, int N) {
    __shared__ float red[4][128];
    int t = threadIdx.x;
    int f = t & 127, sub = t >> 7;

    // Per-thread filter weights in registers, packed in k-pairs
    v2f W0p[N_RBF / 2], W1p[N_RBF / 2], W2p[N_RBF / 2];
    const float* Wbase = filt_W + layer * 384;
#pragma unroll
    for (int j = 0; j < N_RBF / 2; j++) {
        W0p[j] = (v2f){Wbase[(2 * j) * 1152 + f],       Wbase[(2 * j + 1) * 1152 + f]};
        W1p[j] = (v2f){Wbase[(2 * j) * 1152 + 128 + f], Wbase[(2 * j + 1) * 1152 + 128 + f]};
        W2p[j] = (v2f){Wbase[(2 * j) * 1152 + 256 + f], Wbase[(2 * j + 1) * 1152 + 256 + f]};
    }
    float bf0 = filt_b[layer * 384 + f];
    float bf1 = filt_b[layer * 384 + 128 + f];
    float bf2 = filt_b[layer * 384 + 256 + f];

    int i0 = blockIdx.x * NPB;
    for (int nn = 0; nn < NPB; nn++) {
        int i = i0 + nn;
        if (i >= N) break;                       // uniform across block
        int rs = row_ptr[i], re = row_ptr[i + 1];
        float dq = 0.f;
        v2f dm01 = (v2f){0.f, 0.f};
        float dm2 = 0.f;

        for (int e = rs + sub; e < re; e += 2) {
            const float4* g4 = (const float4*)(geom + (size_t)e * 24);
            float4 a  = g4[0];                   // dirx, diry, dirz, fcut
            float4 p0 = g4[1], p1 = g4[2], p2 = g4[3], p3 = g4[4], p4 = g4[5];
            int j = idx_j[e];
            const float* xj = x + (size_t)j * 384;
            const float* mj = mu_in + (size_t)j * 384;
            float xq = xj[f], xr = xj[128 + f], xm = xj[256 + f];
            float m0 = mj[f], m1 = mj[128 + f], m2 = mj[256 + f];

            v2f ph[N_RBF / 2] = {
                (v2f){p0.x, p0.y}, (v2f){p0.z, p0.w},
                (v2f){p1.x, p1.y}, (v2f){p1.z, p1.w},
                (v2f){p2.x, p2.y}, (v2f){p2.z, p2.w},
                (v2f){p3.x, p3.y}, (v2f){p3.z, p3.w},
                (v2f){p4.x, p4.y}, (v2f){p4.z, p4.w}};
            v2f aq = (v2f){0.f, 0.f}, ar = (v2f){0.f, 0.f}, am = (v2f){0.f, 0.f};
#pragma unroll
            for (int k = 0; k < N_RBF / 2; k++) {
                aq += ph[k] * W0p[k];
                ar += ph[k] * W1p[k];
                am += ph[k] * W2p[k];
            }
            float wq = aq.x + aq.y + a.w * bf0;
            float wr = ar.x + ar.y + a.w * bf1;
            float wm = am.x + am.y + a.w * bf2;

            dq += wq * xq;
            float s_r = wr * xr, s_m = wm * xm;
            dm01 += (v2f){s_r, s_r} * (v2f){a.x, a.y} + (v2f){s_m, s_m} * (v2f){m0, m1};
            dm2  += s_r * a.z + s_m * m2;
        }

        if (sub == 1) { red[0][f] = dq; red[1][f] = dm01.x; red[2][f] = dm01.y; red[3][f] = dm2; }
        __syncthreads();
        if (sub == 0) {
            dq += red[0][f];
            float d0 = dm01.x + red[1][f], d1 = dm01.y + red[2][f];
            dm2 += red[3][f];
            q[(size_t)i * 128 + f] += dq;
            size_t base = (size_t)i * 384;
            mu_out[base + f]       = mu_in[base + f] + d0;
            mu_out[base + 128 + f] = mu_in[base + 128 + f] + d1;
            mu_out[base + 256 + f] = mu_in[base + 256 + f] + dm2;
        }
        __syncthreads();
    }
}

// ---------------------------------------------------------------------------
// Mixing block: 8 nodes / block, 256 threads. In-place update of q, mu. (R2)
__global__ __launch_bounds__(256) void k_mix(float* __restrict__ q,
                                             float* __restrict__ mu,
                                             const float* __restrict__ muxW,
                                             const float* __restrict__ W1,
                                             const float* __restrict__ b1,
                                             const float* __restrict__ W2,
                                             const float* __restrict__ b2, int N) {
    __shared__ float mus[8][3][128];
    __shared__ float qs[8][128];
    __shared__ float Vs[8][3][128];
    __shared__ float Ws_[8][3][128];
    __shared__ float vns[8][128];
    __shared__ float hs[8][128];
    int n0 = blockIdx.x * 8;
    int t = threadIdx.x;
    int f = t & 127, nb = t >> 7;

    for (int idx = t; idx < 3072; idx += 256) {
        int n = idx / 384, rem = idx % 384;
        int gn = n0 + n;
        ((float*)mus)[idx] = (gn < N) ? mu[(size_t)gn * 384 + rem] : 0.f;
    }
    for (int idx = t; idx < 1024; idx += 256) {
        int n = idx >> 7, ff = idx & 127;
        int gn = n0 + n;
        qs[n][ff] = (gn < N) ? q[(size_t)gn * 128 + ff] : 0.f;
    }
    __syncthreads();

    {   // mu_mix = mu @ muxW : half nb==0 computes V cols, nb==1 the W cols
        float acc[8][3];
#pragma unroll
        for (int n = 0; n < 8; n++)
#pragma unroll
            for (int c = 0; c < 3; c++) acc[n][c] = 0.f;
        for (int k = 0; k < 128; k++) {
            float w = muxW[k * 256 + nb * 128 + f];
#pragma unroll
            for (int n = 0; n < 8; n++) {
                acc[n][0] += mus[n][0][k] * w;
                acc[n][1] += mus[n][1][k] * w;
                acc[n][2] += mus[n][2][k] * w;
            }
        }
        if (nb == 0) {
#pragma unroll
            for (int n = 0; n < 8; n++)
#pragma unroll
                for (int c = 0; c < 3; c++) Vs[n][c][f] = acc[n][c];
        } else {
#pragma unroll
            for (int n = 0; n < 8; n++)
#pragma unroll
                for (int c = 0; c < 3; c++) Ws_[n][c][f] = acc[n][c];
        }
    }
    __syncthreads();

    for (int idx = t; idx < 1024; idx += 256) {
        int n = idx >> 7, ff = idx & 127;
        float v0 = Vs[n][0][ff], v1 = Vs[n][1][ff], v2 = Vs[n][2][ff];
        vns[n][ff] = sqrtf(v0 * v0 + v1 * v1 + v2 * v2 + 1e-8f);
    }
    __syncthreads();

    {   // h = silu([q, vn] @ W1 + b1)
        float acc[4];
#pragma unroll
        for (int r = 0; r < 4; r++) acc[r] = b1[f];
        for (int k = 0; k < 128; k++) {
            float w = W1[k * 128 + f];
#pragma unroll
            for (int r = 0; r < 4; r++) acc[r] += qs[2 * r + nb][k] * w;
        }
        for (int k = 0; k < 128; k++) {
            float w = W1[(128 + k) * 128 + f];
#pragma unroll
            for (int r = 0; r < 4; r++) acc[r] += vns[2 * r + nb][k] * w;
        }
#pragma unroll
        for (int r = 0; r < 4; r++) {
            float a = acc[r];
            hs[2 * r + nb][f] = a / (1.f + __expf(-a));
        }
    }
    __syncthreads();

    {   // x = h @ W2 + b2 ; then update q, mu
        float x0[4], x1[4], x2[4];
#pragma unroll
        for (int r = 0; r < 4; r++) { x0[r] = b2[f]; x1[r] = b2[128 + f]; x2[r] = b2[256 + f]; }
        for (int k = 0; k < 128; k++) {
            float w0 = W2[k * 384 + f];
            float w1 = W2[k * 384 + 128 + f];
            float w2 = W2[k * 384 + 256 + f];
#pragma unroll
            for (int r = 0; r < 4; r++) {
                float h = hs[2 * r + nb][k];
                x0[r] += h * w0; x1[r] += h * w1; x2[r] += h * w2;
            }
        }
#pragma unroll
        for (int r = 0; r < 4; r++) {
            int n = 2 * r + nb;
            int gn = n0 + n;
            if (gn >= N) continue;
            float S = Vs[n][0][f] * Ws_[n][0][f] + Vs[n][1][f] * Ws_[n][1][f] +
                      Vs[n][2][f] * Ws_[n][2][f];
            q[(size_t)gn * 128 + f] = qs[n][f] + x0[r] + x2[r] * S;
            size_t base = (size_t)gn * 384;
#pragma unroll
            for (int c = 0; c < 3; c++)
                mu[base + c * 128 + f] = mus[n][c][f] + x1[r] * Ws_[n][c][f];
        }
    }
}

// ---------------------------------------------------------------------------
extern "C" void kernel_launch(void* const* d_in, const int* in_sizes, int n_in,
                              void* d_out, int out_size, void* d_ws, size_t ws_size,
                              hipStream_t stream) {
    const int*   Z      = (const int*)d_in[0];
    const float* r_ij   = (const float*)d_in[1];
    const int*   idx_i  = (const int*)d_in[2];
    const int*   idx_j  = (const int*)d_in[3];
    const float* emb    = (const float*)d_in[4];
    const float* filt_W = (const float*)d_in[5];
    const float* filt_b = (const float*)d_in[6];
    const float* int_W1 = (const float*)d_in[7];
    const float* int_b1 = (const float*)d_in[8];
    const float* int_W2 = (const float*)d_in[9];
    const float* int_b2 = (const float*)d_in[10];
    const float* mix_W1 = (const float*)d_in[11];
    const float* mix_b1 = (const float*)d_in[12];
    const float* mix_W2 = (const float*)d_in[13];
    const float* mix_b2 = (const float*)d_in[14];
    const float* mux_W  = (const float*)d_in[15];

    int N = in_sizes[0];
    int E = in_sizes[2];

    float* q   = (float*)d_out;              // [N,128]
    float* muD = q + (size_t)N * 128;        // [N,3,128]

    float* ws   = (float*)d_ws;
    float* geom = ws;                          // E*24
    float* xbuf = geom + (size_t)E * 24;       // N*384
    float* muA  = xbuf + (size_t)N * 384;      // N*384
    int* row_ptr = (int*)(muA + (size_t)N * 384);  // N+1

    k_rowptr<<<(N + 1 + 255) / 256, 256, 0, stream>>>(idx_i, row_ptr, N, E);
    k_init<<<((size_t)N * 384 + 255) / 256, 256, 0, stream>>>(Z, emb, q, muA, N);
    k_geom<<<(E + 255) / 256, 256, 0, stream>>>(r_ij, geom, E);

    float* mu_in = muA;
    float* mu_out = muD;
    for (int l = 0; l < 3; l++) {
        k_node_msg<<<(N + 15) / 16, 256, 0, stream>>>(
            q, int_W1 + (size_t)l * 128 * 128, int_b1 + l * 128,
            int_W2 + (size_t)l * 128 * 384, int_b2 + l * 384, xbuf, N);
        k_edge<<<(N + NPB - 1) / NPB, 256, 0, stream>>>(
            xbuf, mu_in, geom, idx_j, row_ptr, filt_W, filt_b, l, q, mu_out, N);
        k_mix<<<(N + 7) / 8, 256, 0, stream>>>(
            q, mu_out, mux_W + (size_t)l * 128 * 256,
            mix_W1 + (size_t)l * 256 * 128, mix_b1 + l * 128,
            mix_W2 + (size_t)l * 128 * 384, mix_b2 + l * 384, N);
        float* tmp = mu_in; mu_in = mu_out; mu_out = tmp;
    }
}